// Round 7
// baseline (2625.680 us; speedup 1.0000x reference)
//
#include <hip/hip_runtime.h>
#include <stdint.h>

typedef unsigned long long u64;
typedef unsigned int u32;
typedef float f2 __attribute__((ext_vector_type(2)));

__device__ __forceinline__ float rn_mul(float a, float b){ return __fmul_rn(a,b); }
__device__ __forceinline__ float rn_add(float a, float b){ return __fadd_rn(a,b); }
__device__ __forceinline__ float rn_sub(float a, float b){ return __fsub_rn(a,b); }

// monotone float->uint key (total order incl. negatives)
__device__ __forceinline__ u32 fkey(float d){
  u32 b = __float_as_uint(d);
  return b ^ ((u32)((int)b >> 31) | 0x80000000u);
}
__device__ __forceinline__ float unfkey(u32 k){
  const u32 b = (k & 0x80000000u) ? (k ^ 0x80000000u) : ~k;
  return __uint_as_float(b);
}

__device__ __forceinline__ u64 shfl_xor64(u64 v, int mask){
  int lo = __shfl_xor((int)(u32)v, mask, 64);
  int hi = __shfl_xor((int)(u32)(v >> 32), mask, 64);
  return ((u64)(u32)hi << 32) | (u32)lo;
}
__device__ __forceinline__ u64 umin64(u64 a, u64 b){ return a < b ? a : b; }
__device__ __forceinline__ u64 umax64(u64 a, u64 b){ return a > b ? a : b; }

template<int C>
__device__ __forceinline__ u64 dstep64(u64 v){
  const u32 l = (u32)__builtin_amdgcn_update_dpp((int)(u32)v, (int)(u32)v, C, 0xF, 0xF, false);
  const u32 h = (u32)__builtin_amdgcn_update_dpp((int)(u32)(v>>32), (int)(u32)(v>>32), C, 0xF, 0xF, false);
  const u64 o = ((u64)h << 32) | l;
  return o > v ? o : v;
}
// full-wave max: valid in lane 63
__device__ __forceinline__ u64 wave64_max64(u64 v){
  v = dstep64<0x111>(v); v = dstep64<0x112>(v); v = dstep64<0x114>(v);
  v = dstep64<0x118>(v); v = dstep64<0x142>(v); v = dstep64<0x143>(v);
  return v;
}

__device__ __forceinline__ f2 f2max(f2 a, f2 b){
  f2 r; r.x = fmaxf(a.x,b.x); r.y = fmaxf(a.y,b.y); return r;
}

// ---------------------------------------------------------------------------
// FPS with 32-cell exact pruning (octant x radial quartile), 4 cells/wave.
// One block/batch, 512 threads. Per cell: 6 pts/thread in registers, own
// bbox + radial bounds, own cached (maxbits<<32)|~origidx pk. A cell skips
// its update when 0.98*LB^2 >= its own max mind  -- every skipped fminf is
// provably a no-op => bit-identical to the jnp reference. Tie semantics =
// jnp.argmax (max value, smallest original index) exactly.
// No global memory ops inside the loop.
// ---------------------------------------------------------------------------
template<int N, int NT, int M>
__global__ __launch_bounds__(NT)
void fps_kernel(const float* __restrict__ pts, float* __restrict__ npts)
{
#pragma clang fp contract(off)
  constexpr int NW  = NT/64;        // 8 waves
  constexpr int NC  = 32;           // cells, 4 per wave
  constexpr int CAP = 352;          // slots/cell (mean 256, +6.1 sigma)
  constexpr int PPT = 6;            // regs/thread/cell (64*6=384 >= CAP)
  constexpr int PP2 = 3;
  __shared__ u64 part[2][NW];
  __shared__ float SX[NC*CAP], SY[NC*CAP], SZ[NC*CAP];  // staging -> orig-idx table
  __shared__ u32 cnt[NC];
  __shared__ u32 blo[NC][3], bhi[NC][3];
  __shared__ u32 rloS[NC], rhiS[NC];
  __shared__ unsigned short SI[NC*CAP];
  __shared__ unsigned short WX[M];
  const int b = blockIdx.x;
  const float* P = pts + (size_t)b*N*3;
  float* O = npts + (size_t)b*M*3;
  const int tid = threadIdx.x, lane = tid & 63, wv = tid >> 6;

  if (tid < NC) { cnt[tid] = 0; rloS[tid] = 0xFFFFFFFFu; rhiS[tid] = 0u; }
  if (tid < NC*3){ ((u32*)blo)[tid] = 0xFFFFFFFFu; ((u32*)bhi)[tid] = 0u; }
  __syncthreads();

  // cell assignment (octant | radial quartile) + bounds. Partition choice
  // never affects output values -- only pruning quality and layout.
  for (int i = tid; i < N; i += NT){
    const float x = P[3*i], y = P[3*i+1], z = P[3*i+2];
    const float r2 = rn_add(rn_add(rn_mul(x,x),rn_mul(y,y)),rn_mul(z,z));
    const float r  = sqrtf(r2);
    const int band = (r2 < 1.2125f) ? 0 : (r2 < 2.3660f) ? 1 : (r2 < 4.1083f) ? 2 : 3;
    const int oc = ((x<0.f)?1:0)|((y<0.f)?2:0)|((z<0.f)?4:0)|(band<<3);
    const u32 s = atomicAdd(&cnt[oc], 1u);
    if (s < CAP){
      SX[oc*CAP+s]=x; SY[oc*CAP+s]=y; SZ[oc*CAP+s]=z;
      SI[oc*CAP+s]=(unsigned short)i;
    }
    atomicMin(&blo[oc][0],fkey(x)); atomicMax(&bhi[oc][0],fkey(x));
    atomicMin(&blo[oc][1],fkey(y)); atomicMax(&bhi[oc][1],fkey(y));
    atomicMin(&blo[oc][2],fkey(z)); atomicMax(&bhi[oc][2],fkey(z));
    atomicMin(&rloS[oc],fkey(r));   atomicMax(&rhiS[oc],fkey(r));
  }
  __syncthreads();

  const int c0i = 4*wv, c1i = 4*wv+1, c2i = 4*wv+2, c3i = 4*wv+3;
  f2 X0[PP2],Y0[PP2],Z0[PP2],M0[PP2]; u32 O0[PPT];
  f2 X1[PP2],Y1[PP2],Z1[PP2],M1[PP2]; u32 O1[PPT];
  f2 X2[PP2],Y2[PP2],Z2[PP2],M2[PP2]; u32 O2[PPT];
  f2 X3[PP2],Y3[PP2],Z3[PP2],M3[PP2]; u32 O3[PPT];

#define LOADC(cell,Xc,Yc,Zc,Oc)                                               \
  { const u32 cw = cnt[cell]; const int bs = (cell)*CAP;                      \
    _Pragma("unroll")                                                         \
    for (int k = 0; k < PPT; ++k){                                            \
      u32 s = (u32)lane + 64u*(u32)k;                                         \
      if (s >= cw) s -= cw;  if (s >= cw) s -= cw;  if (s >= cw) s -= cw;     \
      Xc_set(Xc,k, SX[bs+s]); Xc_set(Yc,k, SY[bs+s]); Xc_set(Zc,k, SZ[bs+s]); \
      Oc[k] = SI[bs+s];                                                       \
    } }
#define Xc_set(A,k,val) { if((k)&1) A[(k)>>1].y = (val); else A[(k)>>1].x = (val); }
#define Xc_get(A,k) (((k)&1) ? A[(k)>>1].y : A[(k)>>1].x)

  LOADC(c0i,X0,Y0,Z0,O0)
  LOADC(c1i,X1,Y1,Z1,O1)
  LOADC(c2i,X2,Y2,Z2,O2)
  LOADC(c3i,X3,Y3,Z3,O3)

#define RFL(x) __uint_as_float((u32)__builtin_amdgcn_readfirstlane((int)__float_as_uint(x)))
#define LOADB(cell,lox,loy,loz,hix,hiy,hiz,rlo,rhi)                           \
  const float lox=RFL(unfkey(blo[cell][0])), loy=RFL(unfkey(blo[cell][1])),   \
              loz=RFL(unfkey(blo[cell][2]));                                  \
  const float hix=RFL(unfkey(bhi[cell][0])), hiy=RFL(unfkey(bhi[cell][1])),   \
              hiz=RFL(unfkey(bhi[cell][2]));                                  \
  const float rlo=RFL(unfkey(rloS[cell])),   rhi=RFL(unfkey(rhiS[cell]));
  LOADB(c0i,lox0,loy0,loz0,hix0,hiy0,hiz0,rlo0,rhi0)
  LOADB(c1i,lox1,loy1,loz1,hix1,hiy1,hiz1,rlo1,rhi1)
  LOADB(c2i,lox2,loy2,loz2,hix2,hiy2,hiz2,rlo2,rhi2)
  LOADB(c3i,lox3,loy3,loz3,hix3,hiy3,hiz3,rlo3,rhi3)
  __syncthreads();

  // rewrite coord table indexed by ORIGINAL index (dup writes carry same data)
#pragma unroll
  for (int k = 0; k < PPT; ++k){
    SX[O0[k]]=Xc_get(X0,k); SY[O0[k]]=Xc_get(Y0,k); SZ[O0[k]]=Xc_get(Z0,k);
    SX[O1[k]]=Xc_get(X1,k); SY[O1[k]]=Xc_get(Y1,k); SZ[O1[k]]=Xc_get(Z1,k);
    SX[O2[k]]=Xc_get(X2,k); SY[O2[k]]=Xc_get(Y2,k); SZ[O2[k]]=Xc_get(Z2,k);
    SX[O3[k]]=Xc_get(X3,k); SY[O3[k]]=Xc_get(Y3,k); SZ[O3[k]]=Xc_get(Z3,k);
  }
  if (tid == 0) WX[0] = 0;
  __syncthreads();

// per-cell: fused update + tree-max + first-idx scan + u64 wave reduce
#define PKOF(MDc,Oc,bmv,pkh,pkl)                                              \
  { u32 mo = 0xFFFFFFFFu;                                                     \
    _Pragma("unroll")                                                         \
    for (int k = 0; k < PPT; ++k){                                            \
      const float mk = Xc_get(MDc,k);                                         \
      const u32 c_ = (mk == (bmv)) ? Oc[k] : 0xFFFFFFFFu;                     \
      mo = mo < c_ ? mo : c_;                                                 \
    }                                                                         \
    u64 pk = ((u64)__float_as_uint(bmv) << 32) | (u64)(u32)~mo;               \
    pk = wave64_max64(pk);                                                    \
    pkh = (u32)__builtin_amdgcn_readlane((int)(u32)(pk>>32), 63);             \
    pkl = (u32)__builtin_amdgcn_readlane((int)(u32)pk, 63); }

#define UPDC(Xc,Yc,Zc,MDc,Oc,pkh,pkl,ccx,ccy,ccz)                             \
  { const f2 cx2={ccx,ccx}, cy2={ccy,ccy}, cz2={ccz,ccz};                     \
    f2 t[PP2];                                                                \
    _Pragma("unroll")                                                         \
    for (int j = 0; j < PP2; ++j){                                            \
      const f2 dx=Xc[j]-cx2, dy=Yc[j]-cy2, dz=Zc[j]-cz2;                      \
      const f2 d = ((dx*dx) + (dy*dy)) + (dz*dz);                             \
      MDc[j].x = fminf(MDc[j].x, d.x);                                        \
      MDc[j].y = fminf(MDc[j].y, d.y);                                        \
      t[j] = MDc[j];                                                          \
    }                                                                         \
    t[0]=f2max(t[0],t[1]); t[0]=f2max(t[0],t[2]);                             \
    const float bmv = fmaxf(t[0].x, t[0].y);                                  \
    PKOF(MDc,Oc,bmv,pkh,pkl) }

  // init: mind = +inf, then one UPDC vs original point 0 (exact d0)
  u32 pk0h,pk0l,pk1h,pk1l,pk2h,pk2l,pk3h,pk3l;
  {
    const float c0x = SX[0], c0y = SY[0], c0z = SZ[0];
    const f2 inf2 = { __uint_as_float(0x7f800000u), __uint_as_float(0x7f800000u) };
#pragma unroll
    for (int j = 0; j < PP2; ++j){ M0[j]=inf2; M1[j]=inf2; M2[j]=inf2; M3[j]=inf2; }
    UPDC(X0,Y0,Z0,M0,O0,pk0h,pk0l,c0x,c0y,c0z)
    UPDC(X1,Y1,Z1,M1,O1,pk1h,pk1l,c0x,c0y,c0z)
    UPDC(X2,Y2,Z2,M2,O2,pk2h,pk2l,c0x,c0y,c0z)
    UPDC(X3,Y3,Z3,M3,O3,pk3h,pk3l,c0x,c0y,c0z)
  }

#define SKIPTEST(lox,loy,loz,hix,hiy,hiz,rlo,rhi,pkh,lbout)                   \
  float lbout;                                                                \
  { const float tdx = fmaxf(0.f, fmaxf(lox-cx, cx-hix));                      \
    const float tdy = fmaxf(0.f, fmaxf(loy-cy, cy-hiy));                      \
    const float tdz = fmaxf(0.f, fmaxf(loz-cz, cz-hiz));                      \
    float lb = (tdx*tdx + tdy*tdy) + tdz*tdz;                                 \
    const float dr = fmaxf(0.f, fmaxf(rlo-rc, rc-rhi));                       \
    lbout = fmaxf(lb, dr*dr) * 0.98f; }

  for (int it = 1; it < M; ++it){
    if (lane == 0)
      part[it & 1][wv] = umax64(umax64(((u64)pk0h<<32)|pk0l, ((u64)pk1h<<32)|pk1l),
                                umax64(((u64)pk2h<<32)|pk2l, ((u64)pk3h<<32)|pk3l));
    __syncthreads();                       // LDS-only loop
    u64 v = part[it & 1][lane & (NW-1)];
    v = dstep64<0x111>(v); v = dstep64<0x112>(v); v = dstep64<0x114>(v);
    const u32 wl = (u32)__builtin_amdgcn_readlane((int)(u32)v, 7);
    const u32 widx = ~wl;
    if (tid == 0) WX[it] = (unsigned short)widx;
    const float cx = SX[widx], cy = SY[widx], cz = SZ[widx];
    const float rc = sqrtf((cx*cx + cy*cy) + cz*cz);
    SKIPTEST(lox0,loy0,loz0,hix0,hiy0,hiz0,rlo0,rhi0,pk0h,lb0)
    SKIPTEST(lox1,loy1,loz1,hix1,hiy1,hiz1,rlo1,rhi1,pk1h,lb1)
    SKIPTEST(lox2,loy2,loz2,hix2,hiy2,hiz2,rlo2,rhi2,pk2h,lb2)
    SKIPTEST(lox3,loy3,loz3,hix3,hiy3,hiz3,rlo3,rhi3,pk3h,lb3)
    if (lb0 < __uint_as_float(pk0h)){ UPDC(X0,Y0,Z0,M0,O0,pk0h,pk0l,cx,cy,cz) }
    if (lb1 < __uint_as_float(pk1h)){ UPDC(X1,Y1,Z1,M1,O1,pk1h,pk1l,cx,cy,cz) }
    if (lb2 < __uint_as_float(pk2h)){ UPDC(X2,Y2,Z2,M2,O2,pk2h,pk2l,cx,cy,cz) }
    if (lb3 < __uint_as_float(pk3h)){ UPDC(X3,Y3,Z3,M3,O3,pk3h,pk3l,cx,cy,cz) }
  }
  __syncthreads();
  // epilogue: the only global stores
  for (int j = tid; j < M; j += NT){
    const u32 w_ = WX[j];
    O[3*j+0] = SX[w_]; O[3*j+1] = SY[w_]; O[3*j+2] = SZ[w_];
  }
#undef LOADC
#undef LOADB
#undef PKOF
#undef UPDC
#undef SKIPTEST
#undef RFL
#undef Xc_set
#undef Xc_get
}

// ---------------------------------------------------------------------------
// top-4 (ascending) insertion + cross-lane merge helpers
// ---------------------------------------------------------------------------
__device__ __forceinline__ void top4_insert(u64& a0,u64& a1,u64& a2,u64& a3, u64 p){
  if (p < a3){
    const bool c2 = p < a2, c1 = p < a1, c0 = p < a0;
    const u64 n3 = c2 ? a2 : p;
    const u64 n2 = c2 ? (c1 ? a1 : p) : a2;
    const u64 n1 = c1 ? (c0 ? a0 : p) : a1;
    const u64 n0 = c0 ? p : a0;
    a0=n0; a1=n1; a2=n2; a3=n3;
  }
}

__device__ __forceinline__ void merge4(u64& a0, u64& a1, u64& a2, u64& a3, int st)
{
  const u64 b0 = shfl_xor64(a0, st);
  const u64 b1 = shfl_xor64(a1, st);
  const u64 b2 = shfl_xor64(a2, st);
  const u64 b3 = shfl_xor64(a3, st);
  const u64 m0 = umin64(a0, b3);
  const u64 m1 = umin64(a1, b2);
  const u64 m2 = umin64(a2, b1);
  const u64 m3 = umin64(a3, b0);
  const u64 lo02 = umin64(m0,m2), hi02 = umax64(m0,m2);
  const u64 lo13 = umin64(m1,m3), hi13 = umax64(m1,m3);
  a0 = umin64(lo02, lo13); a1 = umax64(lo02, lo13);
  a2 = umin64(hi02, hi13); a3 = umax64(hi02, hi13);
}

// ---------------------------------------------------------------------------
// Level-1: kNN(k=4) + MLP(3->8->16->16) + max over k -> f1
// ---------------------------------------------------------------------------
template<int N, int M, int CH>
__global__ __launch_bounds__(256)
void knn_mlp1_kernel(const float* __restrict__ q, const float* __restrict__ pts,
                     const float* __restrict__ w1, const float* __restrict__ b1,
                     const float* __restrict__ w2, const float* __restrict__ b2,
                     const float* __restrict__ w3, const float* __restrict__ b3,
                     float* __restrict__ f1)
{
  __shared__ float4 s4[CH];
  constexpr int QPB = 64;
  const int blk = blockIdx.x;
  const int b = blk / (M / QPB);
  const int chunk = blk % (M / QPB);
  const int tid = threadIdx.x;
  const int g = tid >> 2;
  const int r = tid & 3;
  const int qi = chunk * QPB + g;
  const float* qp = q + ((size_t)b * M + qi) * 3;
  const float qx = qp[0], qy = qp[1], qz = qp[2];
  const float sumq = rn_add(rn_add(rn_mul(qx,qx), rn_mul(qy,qy)), rn_mul(qz,qz));
  const float* P = pts + (size_t)b * N * 3;

  u64 a0=~0ull, a1=~0ull, a2=~0ull, a3=~0ull;
  for (int c0 = 0; c0 < N; c0 += CH){
    for (int i = tid; i < CH; i += 256){
      const float x = P[3*(c0+i)+0], y = P[3*(c0+i)+1], z = P[3*(c0+i)+2];
      s4[i] = make_float4(x, y, z,
          rn_add(rn_add(rn_mul(x,x), rn_mul(y,y)), rn_mul(z,z)));
    }
    __syncthreads();
#pragma unroll 4
    for (int jj = r; jj < CH; jj += 4){
      const float4 v = s4[jj];
      const float dot = rn_add(rn_add(rn_mul(qx,v.x), rn_mul(qy,v.y)),
                               rn_mul(qz,v.z));
      const float d = rn_add(rn_sub(sumq, rn_mul(2.0f, dot)), v.w);
      top4_insert(a0,a1,a2,a3, ((u64)fkey(d) << 32) | (u32)(c0+jj));
    }
    __syncthreads();
  }
  merge4(a0,a1,a2,a3,1);
  merge4(a0,a1,a2,a3,2);
  const u64 selp = (r==0) ? a0 : (r==1) ? a1 : (r==2) ? a2 : a3;
  const u32 nidx = (u32)selp;

  const float nx = P[3*nidx+0], ny = P[3*nidx+1], nz = P[3*nidx+2];
  float h1[8];
#pragma unroll
  for (int c = 0; c < 8; ++c){
    float acc = b1[c];
    acc = fmaf(nx, w1[0*8+c], acc);
    acc = fmaf(ny, w1[1*8+c], acc);
    acc = fmaf(nz, w1[2*8+c], acc);
    h1[c] = fmaxf(acc, 0.0f);
  }
  float h2[16];
#pragma unroll
  for (int c = 0; c < 16; ++c){
    float acc = b2[c];
#pragma unroll
    for (int k = 0; k < 8; ++k) acc = fmaf(h1[k], w2[k*16+c], acc);
    h2[c] = fmaxf(acc, 0.0f);
  }
  float* fo = f1 + ((size_t)b * M + qi) * 16;
#pragma unroll
  for (int c = 0; c < 16; ++c){
    float acc = b3[c];
#pragma unroll
    for (int k = 0; k < 16; ++k) acc = fmaf(h2[k], w3[k*16+c], acc);
    float v = fmaxf(acc, 0.0f);
    v = fmaxf(v, __shfl_xor(v, 1, 64));
    v = fmaxf(v, __shfl_xor(v, 2, 64));
    if (r == 0) fo[c] = v;
  }
}

// ---------------------------------------------------------------------------
// Level-2: kNN(k=4) over npts1 + gather f1 + MLP(16->32->64->64) + max -> f2
// Queries = first 512 rows of npts1 (FPS nesting property, exact).
// ---------------------------------------------------------------------------
__global__ __launch_bounds__(256)
void knn_mlp2_kernel(const float* __restrict__ q, const float* __restrict__ pts,
                     const float* __restrict__ f1,
                     const float* __restrict__ w1, const float* __restrict__ b1,
                     const float* __restrict__ w2, const float* __restrict__ b2,
                     const float* __restrict__ w3, const float* __restrict__ b3,
                     float* __restrict__ f2)
{
  constexpr int N = 2048, M = 512, QPB = 64, QSTR = 2048;
  __shared__ float4 s4[N];
  const int blk = blockIdx.x;
  const int b = blk / (M / QPB);
  const int chunk = blk % (M / QPB);
  const int tid = threadIdx.x;
  const int g = tid >> 2;
  const int r = tid & 3;
  const int qi = chunk * QPB + g;
  const float* qp = q + ((size_t)b * QSTR + qi) * 3;
  const float qx = qp[0], qy = qp[1], qz = qp[2];
  const float sumq = rn_add(rn_add(rn_mul(qx,qx), rn_mul(qy,qy)), rn_mul(qz,qz));
  const float* P = pts + (size_t)b * N * 3;

  for (int i = tid; i < N; i += 256){
    const float x = P[3*i+0], y = P[3*i+1], z = P[3*i+2];
    s4[i] = make_float4(x, y, z,
        rn_add(rn_add(rn_mul(x,x), rn_mul(y,y)), rn_mul(z,z)));
  }
  __syncthreads();

  u64 a0=~0ull, a1=~0ull, a2=~0ull, a3=~0ull;
#pragma unroll 4
  for (int j = r; j < N; j += 4){
    const float4 v = s4[j];
    const float dot = rn_add(rn_add(rn_mul(qx,v.x), rn_mul(qy,v.y)),
                             rn_mul(qz,v.z));
    const float d = rn_add(rn_sub(sumq, rn_mul(2.0f, dot)), v.w);
    top4_insert(a0,a1,a2,a3, ((u64)fkey(d) << 32) | (u32)j);
  }
  merge4(a0,a1,a2,a3,1);
  merge4(a0,a1,a2,a3,2);
  const u64 selp = (r==0) ? a0 : (r==1) ? a1 : (r==2) ? a2 : a3;
  const u32 nidx = (u32)selp;

  const float* fv = f1 + ((size_t)b * 2048 + nidx) * 16;
  float x[16];
#pragma unroll
  for (int i = 0; i < 4; ++i){
    const float4 v = ((const float4*)fv)[i];
    x[4*i+0]=v.x; x[4*i+1]=v.y; x[4*i+2]=v.z; x[4*i+3]=v.w;
  }
  float h1[32];
#pragma unroll
  for (int c = 0; c < 32; ++c){
    float acc = b1[c];
#pragma unroll
    for (int k = 0; k < 16; ++k) acc = fmaf(x[k], w1[k*32+c], acc);
    h1[c] = fmaxf(acc, 0.0f);
  }
  float h2[64];
#pragma unroll
  for (int c = 0; c < 64; ++c){
    float acc = b2[c];
#pragma unroll
    for (int k = 0; k < 32; ++k) acc = fmaf(h1[k], w2[k*64+c], acc);
    h2[c] = fmaxf(acc, 0.0f);
  }
  float* fo = f2 + ((size_t)b * M + qi) * 64;
#pragma unroll
  for (int c = 0; c < 64; ++c){
    float acc = b3[c];
#pragma unroll
    for (int k = 0; k < 64; ++k) acc = fmaf(h2[k], w3[k*64+c], acc);
    float v = fmaxf(acc, 0.0f);
    v = fmaxf(v, __shfl_xor(v, 1, 64));
    v = fmaxf(v, __shfl_xor(v, 2, 64));
    if (r == 0) fo[c] = v;
  }
}

// ---------------------------------------------------------------------------
// Level-3: MLP(64->128->256->256) on f2 + global max over 512 points/batch.
// ---------------------------------------------------------------------------
__global__ __launch_bounds__(256)
void mlp3_kernel(const float* __restrict__ f2,
                 const float* __restrict__ w1, const float* __restrict__ b1,
                 const float* __restrict__ w2, const float* __restrict__ b2,
                 const float* __restrict__ w3, const float* __restrict__ b3,
                 float* __restrict__ out)
{
  constexpr int P = 16;
  __shared__ float X [P][64];
  __shared__ float H1[P][128];
  __shared__ float H2[P][256];
  __shared__ float PM[4][256];
  const int blk = blockIdx.x;
  const int b  = blk >> 5;
  const int pc = blk & 31;
  const int tid = threadIdx.x;
  const float* F = f2 + ((size_t)b * 512 + (size_t)pc * P) * 64;
  { const float4 v = ((const float4*)F)[tid]; ((float4*)&X[0][0])[tid] = v; }
  __syncthreads();
  {
    const int p = tid >> 4, c0 = (tid & 15) * 8;
    float acc[8];
#pragma unroll
    for (int i = 0; i < 8; ++i) acc[i] = b1[c0+i];
    for (int k = 0; k < 64; ++k){
      const float xv = X[p][k];
      const float4 wa = *(const float4*)&w1[k*128 + c0];
      const float4 wb = *(const float4*)&w1[k*128 + c0 + 4];
      acc[0]=fmaf(xv,wa.x,acc[0]); acc[1]=fmaf(xv,wa.y,acc[1]);
      acc[2]=fmaf(xv,wa.z,acc[2]); acc[3]=fmaf(xv,wa.w,acc[3]);
      acc[4]=fmaf(xv,wb.x,acc[4]); acc[5]=fmaf(xv,wb.y,acc[5]);
      acc[6]=fmaf(xv,wb.z,acc[6]); acc[7]=fmaf(xv,wb.w,acc[7]);
    }
#pragma unroll
    for (int i = 0; i < 8; ++i) H1[p][c0+i] = fmaxf(acc[i], 0.0f);
  }
  __syncthreads();
  {
    const int p = tid >> 4, c0 = (tid & 15) * 16;
    float acc[16];
#pragma unroll
    for (int i = 0; i < 16; ++i) acc[i] = b2[c0+i];
    for (int k = 0; k < 128; ++k){
      const float xv = H1[p][k];
#pragma unroll
      for (int i4 = 0; i4 < 4; ++i4){
        const float4 wv = *(const float4*)&w2[k*256 + c0 + 4*i4];
        acc[4*i4+0]=fmaf(xv,wv.x,acc[4*i4+0]);
        acc[4*i4+1]=fmaf(xv,wv.y,acc[4*i4+1]);
        acc[4*i4+2]=fmaf(xv,wv.z,acc[4*i4+2]);
        acc[4*i4+3]=fmaf(xv,wv.w,acc[4*i4+3]);
      }
    }
#pragma unroll
    for (int i = 0; i < 16; ++i) H2[p][c0+i] = fmaxf(acc[i], 0.0f);
  }
  __syncthreads();
  {
    const int pg = tid >> 6, c0 = (tid & 63) * 4;
    float acc[4][4];
#pragma unroll
    for (int p4 = 0; p4 < 4; ++p4)
#pragma unroll
      for (int i = 0; i < 4; ++i) acc[p4][i] = b3[c0+i];
    for (int k = 0; k < 256; ++k){
      const float4 wv = *(const float4*)&w3[k*256 + c0];
#pragma unroll
      for (int p4 = 0; p4 < 4; ++p4){
        const float xv = H2[pg*4+p4][k];
        acc[p4][0]=fmaf(xv,wv.x,acc[p4][0]);
        acc[p4][1]=fmaf(xv,wv.y,acc[p4][1]);
        acc[p4][2]=fmaf(xv,wv.z,acc[p4][2]);
        acc[p4][3]=fmaf(xv,wv.w,acc[p4][3]);
      }
    }
    float4 mx;
    mx.x = fmaxf(fmaxf(fmaxf(acc[0][0],0.f),fmaxf(acc[1][0],0.f)),
                 fmaxf(fmaxf(acc[2][0],0.f),fmaxf(acc[3][0],0.f)));
    mx.y = fmaxf(fmaxf(fmaxf(acc[0][1],0.f),fmaxf(acc[1][1],0.f)),
                 fmaxf(fmaxf(acc[2][1],0.f),fmaxf(acc[3][1],0.f)));
    mx.z = fmaxf(fmaxf(fmaxf(acc[0][2],0.f),fmaxf(acc[1][2],0.f)),
                 fmaxf(fmaxf(acc[2][2],0.f),fmaxf(acc[3][2],0.f)));
    mx.w = fmaxf(fmaxf(fmaxf(acc[0][3],0.f),fmaxf(acc[1][3],0.f)),
                 fmaxf(fmaxf(acc[2][3],0.f),fmaxf(acc[3][3],0.f)));
    *(float4*)&PM[pg][c0] = mx;
  }
  __syncthreads();
  {
    const float m = fmaxf(fmaxf(PM[0][tid], PM[1][tid]),
                          fmaxf(PM[2][tid], PM[3][tid]));
    atomicMax((int*)(out + b*256 + tid), __float_as_int(m));
  }
}

// ---------------------------------------------------------------------------
extern "C" void kernel_launch(void* const* d_in, const int* in_sizes, int n_in,
                              void* d_out, int out_size, void* d_ws, size_t ws_size,
                              hipStream_t stream)
{
  const float* pts  = (const float*)d_in[0];
  // d_in[1] = batch (int64) -- implied by uniform layout, unused
  const float* p1w1 = (const float*)d_in[2];
  const float* p1b1 = (const float*)d_in[3];
  const float* p1w2 = (const float*)d_in[4];
  const float* p1b2 = (const float*)d_in[5];
  const float* p1w3 = (const float*)d_in[6];
  const float* p1b3 = (const float*)d_in[7];
  const float* p2w1 = (const float*)d_in[8];
  const float* p2b1 = (const float*)d_in[9];
  const float* p2w2 = (const float*)d_in[10];
  const float* p2b2 = (const float*)d_in[11];
  const float* p2w3 = (const float*)d_in[12];
  const float* p2b3 = (const float*)d_in[13];
  const float* p3w1 = (const float*)d_in[14];
  const float* p3b1 = (const float*)d_in[15];
  const float* p3w2 = (const float*)d_in[16];
  const float* p3b2 = (const float*)d_in[17];
  const float* p3w3 = (const float*)d_in[18];
  const float* p3b3 = (const float*)d_in[19];

  float* ws = (float*)d_ws;
  size_t o = 0;
  float* npts1 = ws + o; o += (size_t)8*2048*3;
  float* f1    = ws + o; o += (size_t)8*2048*16;
  float* f2    = ws + o; o += (size_t)8*512*64;

  fps_kernel<8192,512,2048><<<8, 512, 0, stream>>>(pts, npts1);
  knn_mlp1_kernel<8192,2048,2048><<<8*32, 256, 0, stream>>>(npts1, pts,
      p1w1, p1b1, p1w2, p1b2, p1w3, p1b3, f1);
  // fps level-2 eliminated: fps(npts1,512) == npts1[:512] (nesting property)
  knn_mlp2_kernel<<<8*8, 256, 0, stream>>>(npts1, npts1, f1,
      p2w1, p2b1, p2w2, p2b2, p2w3, p2b3, f2);
  hipMemsetAsync(d_out, 0, (size_t)out_size * sizeof(float), stream);
  mlp3_kernel<<<8*32, 256, 0, stream>>>(f2,
      p3w1, p3b1, p3w2, p3b2, p3w3, p3b3, (float*)d_out);
}

// Round 8
// 2268.422 us; speedup vs baseline: 1.1575x; 1.1575x over previous
//
#include <hip/hip_runtime.h>
#include <stdint.h>

typedef unsigned long long u64;
typedef unsigned int u32;
typedef float f2 __attribute__((ext_vector_type(2)));

__device__ __forceinline__ float rn_mul(float a, float b){ return __fmul_rn(a,b); }
__device__ __forceinline__ float rn_add(float a, float b){ return __fadd_rn(a,b); }
__device__ __forceinline__ float rn_sub(float a, float b){ return __fsub_rn(a,b); }

// monotone float->uint key (for knn; handles tiny negative cancellation)
__device__ __forceinline__ u32 fkey(float d){
  u32 b = __float_as_uint(d);
  return b ^ ((u32)((int)b >> 31) | 0x80000000u);
}

__device__ __forceinline__ u64 shfl_xor64(u64 v, int mask){
  int lo = __shfl_xor((int)(u32)v, mask, 64);
  int hi = __shfl_xor((int)(u32)(v >> 32), mask, 64);
  return ((u64)(u32)hi << 32) | (u32)lo;
}
__device__ __forceinline__ u64 umin64(u64 a, u64 b){ return a < b ? a : b; }
__device__ __forceinline__ u64 umax64(u64 a, u64 b){ return a > b ? a : b; }

template<int C>
__device__ __forceinline__ u64 dstep64(u64 v){
  const u32 l = (u32)__builtin_amdgcn_update_dpp((int)(u32)v, (int)(u32)v, C, 0xF, 0xF, false);
  const u32 h = (u32)__builtin_amdgcn_update_dpp((int)(u32)(v>>32), (int)(u32)(v>>32), C, 0xF, 0xF, false);
  const u64 o = ((u64)h << 32) | l;
  return o > v ? o : v;
}
// full-wave max: valid in lane 63
__device__ __forceinline__ u64 wave64_max64(u64 v){
  v = dstep64<0x111>(v); v = dstep64<0x112>(v); v = dstep64<0x114>(v);
  v = dstep64<0x118>(v); v = dstep64<0x142>(v); v = dstep64<0x143>(v);
  return v;
}

// ---------------------------------------------------------------------------
// FPS: one block per batch, NT=256 (1 wave/SIMD -> solo issue), 32 pts/thread
// f2-packed. Per iter: fused update; per-point u64 pack (mind_bits<<32)|~gidx
// reduced by a 31-op max-tree (replaces tree-max + serial index scan); 6-step
// u64 DPP wave reduce; lane63 publishes; barrier; red4 (2 DPP steps) over 4
// wave partials; b128 coord broadcast. No global ops in loop; winners to LDS
// u16 list, stored in epilogue. Tie semantics = jnp.argmax exactly.
// ---------------------------------------------------------------------------
template<int N, int NT, int M>
__global__ __launch_bounds__(NT)
void fps_kernel(const float* __restrict__ pts, float* __restrict__ npts)
{
#pragma clang fp contract(off)
  constexpr int PPT = N / NT;          // 32
  constexpr int PP2 = PPT / 2;         // 16
  constexpr int NW  = NT / 64;         // 4
  __shared__ float4 sp[N];             // 128 KB coord table
  __shared__ unsigned short WX[M];     // winner idx per iteration
  __shared__ u64 part[2][NW];
  const int b = blockIdx.x;
  const float* P = pts + (size_t)b * N * 3;
  float* O = npts + (size_t)b * M * 3;
  const int tid = threadIdx.x, lane = tid & 63, wv = tid >> 6;

  for (int i = tid; i < N; i += NT)
    sp[i] = make_float4(P[3*i+0], P[3*i+1], P[3*i+2], 0.0f);
  if (tid == 0) WX[0] = 0;
  __syncthreads();

  f2 rx[PP2], ry[PP2], rz[PP2], mind[PP2];
  const float4 c0 = sp[0];
  {
    const f2 cx2 = {c0.x,c0.x}, cy2 = {c0.y,c0.y}, cz2 = {c0.z,c0.z};
#pragma unroll
    for (int j = 0; j < PP2; ++j){
      const float4 va = sp[tid + (2*j+0)*NT];
      const float4 vb = sp[tid + (2*j+1)*NT];
      rx[j] = f2{va.x, vb.x}; ry[j] = f2{va.y, vb.y}; rz[j] = f2{va.z, vb.z};
      const f2 dx = rx[j]-cx2, dy = ry[j]-cy2, dz = rz[j]-cz2;
      mind[j] = ((dx*dx) + (dy*dy)) + (dz*dz);   // v_pk_*, IEEE rn
    }
  }

  // per-point u64 pack + 31-op max-tree + wave reduce (lane 63 valid)
#define LANEPK(dstpk)                                                         \
  {                                                                           \
    u64 p_[PPT];                                                              \
    _Pragma("unroll")                                                         \
    for (int k = 0; k < PPT; ++k){                                            \
      const float mk = (k&1) ? mind[k>>1].y : mind[k>>1].x;                   \
      p_[k] = ((u64)__float_as_uint(mk) << 32)                                \
            | (u64)(u32)~(u32)(tid + k*NT);                                   \
    }                                                                         \
    _Pragma("unroll")                                                         \
    for (int s = PPT/2; s > 0; s >>= 1)                                       \
      for (int i = 0; i < s; ++i) p_[i] = umax64(p_[i], p_[i+s]);             \
    (dstpk) = wave64_max64(p_[0]);                                            \
  }

  u64 mypk; LANEPK(mypk)

  for (int it = 1; it < M; ++it){
    if (lane == 63) part[it & 1][wv] = mypk;
    __syncthreads();                   // LDS-only loop
    u64 v = part[it & 1][lane & (NW-1)];
    v = dstep64<0x111>(v); v = dstep64<0x112>(v);
    const u32 wl = (u32)__builtin_amdgcn_readlane((int)(u32)v, 3);
    const u32 widx = ~wl;
    if (tid == 0) WX[it] = (unsigned short)widx;
    const float4 c = sp[widx];         // single b128 broadcast read
    const f2 cx2 = {c.x,c.x}, cy2 = {c.y,c.y}, cz2 = {c.z,c.z};
#pragma unroll
    for (int j = 0; j < PP2; ++j){
      const f2 dx = rx[j]-cx2, dy = ry[j]-cy2, dz = rz[j]-cz2;
      const f2 d = ((dx*dx) + (dy*dy)) + (dz*dz);
      mind[j].x = fminf(mind[j].x, d.x);
      mind[j].y = fminf(mind[j].y, d.y);
    }
    LANEPK(mypk)
  }
  __syncthreads();
  // epilogue: the only global stores
  for (int j = tid; j < M; j += NT){
    const float4 v = sp[WX[j]];
    O[3*j+0] = v.x; O[3*j+1] = v.y; O[3*j+2] = v.z;
  }
#undef LANEPK
}

// ---------------------------------------------------------------------------
// top-4 (ascending) insertion + merge helpers
// ---------------------------------------------------------------------------
__device__ __forceinline__ void top4_insert(u64& a0,u64& a1,u64& a2,u64& a3, u64 p){
  if (p < a3){
    const bool c2 = p < a2, c1 = p < a1, c0 = p < a0;
    const u64 n3 = c2 ? a2 : p;
    const u64 n2 = c2 ? (c1 ? a1 : p) : a2;
    const u64 n1 = c1 ? (c0 ? a0 : p) : a1;
    const u64 n0 = c0 ? p : a0;
    a0=n0; a1=n1; a2=n2; a3=n3;
  }
}

// merge sorted quad (a) with sorted quad (b) -> a = 4 smallest, sorted
__device__ __forceinline__ void merge4_local(u64& a0,u64& a1,u64& a2,u64& a3,
                                             u64 b0,u64 b1,u64 b2,u64 b3){
  const u64 m0 = umin64(a0, b3);
  const u64 m1 = umin64(a1, b2);
  const u64 m2 = umin64(a2, b1);
  const u64 m3 = umin64(a3, b0);
  const u64 lo02 = umin64(m0,m2), hi02 = umax64(m0,m2);
  const u64 lo13 = umin64(m1,m3), hi13 = umax64(m1,m3);
  a0 = umin64(lo02, lo13); a1 = umax64(lo02, lo13);
  a2 = umin64(hi02, hi13); a3 = umax64(hi02, hi13);
}

__device__ __forceinline__ void merge4(u64& a0, u64& a1, u64& a2, u64& a3, int st)
{
  const u64 b0 = shfl_xor64(a0, st);
  const u64 b1 = shfl_xor64(a1, st);
  const u64 b2 = shfl_xor64(a2, st);
  const u64 b3 = shfl_xor64(a3, st);
  merge4_local(a0,a1,a2,a3, b0,b1,b2,b3);
}

// ---------------------------------------------------------------------------
// Level-1: kNN(k=4) + MLP(3->8->16->16) + max over k -> f1
// Dual top-4 accumulator streams per lane (halves serial insert dependency).
// ---------------------------------------------------------------------------
template<int N, int M, int CH>
__global__ __launch_bounds__(256)
void knn_mlp1_kernel(const float* __restrict__ q, const float* __restrict__ pts,
                     const float* __restrict__ w1, const float* __restrict__ b1,
                     const float* __restrict__ w2, const float* __restrict__ b2,
                     const float* __restrict__ w3, const float* __restrict__ b3,
                     float* __restrict__ f1)
{
  __shared__ float4 s4[CH];
  constexpr int QPB = 64;
  const int blk = blockIdx.x;
  const int b = blk / (M / QPB);
  const int chunk = blk % (M / QPB);
  const int tid = threadIdx.x;
  const int g = tid >> 2;
  const int r = tid & 3;
  const int qi = chunk * QPB + g;
  const float* qp = q + ((size_t)b * M + qi) * 3;
  const float qx = qp[0], qy = qp[1], qz = qp[2];
  const float sumq = rn_add(rn_add(rn_mul(qx,qx), rn_mul(qy,qy)), rn_mul(qz,qz));
  const float* P = pts + (size_t)b * N * 3;

  u64 a0=~0ull, a1=~0ull, a2=~0ull, a3=~0ull;   // stream A
  u64 e0=~0ull, e1=~0ull, e2=~0ull, e3=~0ull;   // stream B
  for (int c0 = 0; c0 < N; c0 += CH){
    for (int i = tid; i < CH; i += 256){
      const float x = P[3*(c0+i)+0], y = P[3*(c0+i)+1], z = P[3*(c0+i)+2];
      s4[i] = make_float4(x, y, z,
          rn_add(rn_add(rn_mul(x,x), rn_mul(y,y)), rn_mul(z,z)));
    }
    __syncthreads();
#pragma unroll 2
    for (int jj = r; jj < CH; jj += 8){
      { const float4 v = s4[jj];
        const float dot = rn_add(rn_add(rn_mul(qx,v.x), rn_mul(qy,v.y)),
                                 rn_mul(qz,v.z));
        const float d = rn_add(rn_sub(sumq, rn_mul(2.0f, dot)), v.w);
        top4_insert(a0,a1,a2,a3, ((u64)fkey(d) << 32) | (u32)(c0+jj)); }
      { const float4 v = s4[jj+4];
        const float dot = rn_add(rn_add(rn_mul(qx,v.x), rn_mul(qy,v.y)),
                                 rn_mul(qz,v.z));
        const float d = rn_add(rn_sub(sumq, rn_mul(2.0f, dot)), v.w);
        top4_insert(e0,e1,e2,e3, ((u64)fkey(d) << 32) | (u32)(c0+jj+4)); }
    }
    __syncthreads();
  }
  merge4_local(a0,a1,a2,a3, e0,e1,e2,e3);
  merge4(a0,a1,a2,a3,1);
  merge4(a0,a1,a2,a3,2);
  const u64 selp = (r==0) ? a0 : (r==1) ? a1 : (r==2) ? a2 : a3;
  const u32 nidx = (u32)selp;

  const float nx = P[3*nidx+0], ny = P[3*nidx+1], nz = P[3*nidx+2];
  float h1[8];
#pragma unroll
  for (int c = 0; c < 8; ++c){
    float acc = b1[c];
    acc = fmaf(nx, w1[0*8+c], acc);
    acc = fmaf(ny, w1[1*8+c], acc);
    acc = fmaf(nz, w1[2*8+c], acc);
    h1[c] = fmaxf(acc, 0.0f);
  }
  float h2[16];
#pragma unroll
  for (int c = 0; c < 16; ++c){
    float acc = b2[c];
#pragma unroll
    for (int k = 0; k < 8; ++k) acc = fmaf(h1[k], w2[k*16+c], acc);
    h2[c] = fmaxf(acc, 0.0f);
  }
  float* fo = f1 + ((size_t)b * M + qi) * 16;
#pragma unroll
  for (int c = 0; c < 16; ++c){
    float acc = b3[c];
#pragma unroll
    for (int k = 0; k < 16; ++k) acc = fmaf(h2[k], w3[k*16+c], acc);
    float v = fmaxf(acc, 0.0f);
    v = fmaxf(v, __shfl_xor(v, 1, 64));
    v = fmaxf(v, __shfl_xor(v, 2, 64));
    if (r == 0) fo[c] = v;
  }
}

// ---------------------------------------------------------------------------
// Level-2: kNN(k=4) over npts1 + gather f1 + MLP(16->32->64->64) + max -> f2
// Queries = first 512 rows of npts1 (FPS nesting property, exact).
// ---------------------------------------------------------------------------
__global__ __launch_bounds__(256)
void knn_mlp2_kernel(const float* __restrict__ q, const float* __restrict__ pts,
                     const float* __restrict__ f1,
                     const float* __restrict__ w1, const float* __restrict__ b1,
                     const float* __restrict__ w2, const float* __restrict__ b2,
                     const float* __restrict__ w3, const float* __restrict__ b3,
                     float* __restrict__ f2)
{
  constexpr int N = 2048, M = 512, QPB = 64, QSTR = 2048;
  __shared__ float4 s4[N];
  const int blk = blockIdx.x;
  const int b = blk / (M / QPB);
  const int chunk = blk % (M / QPB);
  const int tid = threadIdx.x;
  const int g = tid >> 2;
  const int r = tid & 3;
  const int qi = chunk * QPB + g;
  const float* qp = q + ((size_t)b * QSTR + qi) * 3;
  const float qx = qp[0], qy = qp[1], qz = qp[2];
  const float sumq = rn_add(rn_add(rn_mul(qx,qx), rn_mul(qy,qy)), rn_mul(qz,qz));
  const float* P = pts + (size_t)b * N * 3;

  for (int i = tid; i < N; i += 256){
    const float x = P[3*i+0], y = P[3*i+1], z = P[3*i+2];
    s4[i] = make_float4(x, y, z,
        rn_add(rn_add(rn_mul(x,x), rn_mul(y,y)), rn_mul(z,z)));
  }
  __syncthreads();

  u64 a0=~0ull, a1=~0ull, a2=~0ull, a3=~0ull;
  u64 e0=~0ull, e1=~0ull, e2=~0ull, e3=~0ull;
#pragma unroll 2
  for (int j = r; j < N; j += 8){
    { const float4 v = s4[j];
      const float dot = rn_add(rn_add(rn_mul(qx,v.x), rn_mul(qy,v.y)),
                               rn_mul(qz,v.z));
      const float d = rn_add(rn_sub(sumq, rn_mul(2.0f, dot)), v.w);
      top4_insert(a0,a1,a2,a3, ((u64)fkey(d) << 32) | (u32)j); }
    { const float4 v = s4[j+4];
      const float dot = rn_add(rn_add(rn_mul(qx,v.x), rn_mul(qy,v.y)),
                               rn_mul(qz,v.z));
      const float d = rn_add(rn_sub(sumq, rn_mul(2.0f, dot)), v.w);
      top4_insert(e0,e1,e2,e3, ((u64)fkey(d) << 32) | (u32)(j+4)); }
  }
  merge4_local(a0,a1,a2,a3, e0,e1,e2,e3);
  merge4(a0,a1,a2,a3,1);
  merge4(a0,a1,a2,a3,2);
  const u64 selp = (r==0) ? a0 : (r==1) ? a1 : (r==2) ? a2 : a3;
  const u32 nidx = (u32)selp;

  const float* fv = f1 + ((size_t)b * 2048 + nidx) * 16;
  float x[16];
#pragma unroll
  for (int i = 0; i < 4; ++i){
    const float4 v = ((const float4*)fv)[i];
    x[4*i+0]=v.x; x[4*i+1]=v.y; x[4*i+2]=v.z; x[4*i+3]=v.w;
  }
  float h1[32];
#pragma unroll
  for (int c = 0; c < 32; ++c){
    float acc = b1[c];
#pragma unroll
    for (int k = 0; k < 16; ++k) acc = fmaf(x[k], w1[k*32+c], acc);
    h1[c] = fmaxf(acc, 0.0f);
  }
  float h2[64];
#pragma unroll
  for (int c = 0; c < 64; ++c){
    float acc = b2[c];
#pragma unroll
    for (int k = 0; k < 32; ++k) acc = fmaf(h1[k], w2[k*64+c], acc);
    h2[c] = fmaxf(acc, 0.0f);
  }
  float* fo = f2 + ((size_t)b * M + qi) * 64;
#pragma unroll
  for (int c = 0; c < 64; ++c){
    float acc = b3[c];
#pragma unroll
    for (int k = 0; k < 64; ++k) acc = fmaf(h2[k], w3[k*64+c], acc);
    float v = fmaxf(acc, 0.0f);
    v = fmaxf(v, __shfl_xor(v, 1, 64));
    v = fmaxf(v, __shfl_xor(v, 2, 64));
    if (r == 0) fo[c] = v;
  }
}

// ---------------------------------------------------------------------------
// Level-3: MLP(64->128->256->256) on f2 + global max over 512 points/batch.
// ---------------------------------------------------------------------------
__global__ __launch_bounds__(256)
void mlp3_kernel(const float* __restrict__ f2,
                 const float* __restrict__ w1, const float* __restrict__ b1,
                 const float* __restrict__ w2, const float* __restrict__ b2,
                 const float* __restrict__ w3, const float* __restrict__ b3,
                 float* __restrict__ out)
{
  constexpr int P = 16;
  __shared__ float X [P][64];
  __shared__ float H1[P][128];
  __shared__ float H2[P][256];
  __shared__ float PM[4][256];
  const int blk = blockIdx.x;
  const int b  = blk >> 5;
  const int pc = blk & 31;
  const int tid = threadIdx.x;
  const float* F = f2 + ((size_t)b * 512 + (size_t)pc * P) * 64;
  { const float4 v = ((const float4*)F)[tid]; ((float4*)&X[0][0])[tid] = v; }
  __syncthreads();
  {
    const int p = tid >> 4, c0 = (tid & 15) * 8;
    float acc[8];
#pragma unroll
    for (int i = 0; i < 8; ++i) acc[i] = b1[c0+i];
    for (int k = 0; k < 64; ++k){
      const float xv = X[p][k];
      const float4 wa = *(const float4*)&w1[k*128 + c0];
      const float4 wb = *(const float4*)&w1[k*128 + c0 + 4];
      acc[0]=fmaf(xv,wa.x,acc[0]); acc[1]=fmaf(xv,wa.y,acc[1]);
      acc[2]=fmaf(xv,wa.z,acc[2]); acc[3]=fmaf(xv,wa.w,acc[3]);
      acc[4]=fmaf(xv,wb.x,acc[4]); acc[5]=fmaf(xv,wb.y,acc[5]);
      acc[6]=fmaf(xv,wb.z,acc[6]); acc[7]=fmaf(xv,wb.w,acc[7]);
    }
#pragma unroll
    for (int i = 0; i < 8; ++i) H1[p][c0+i] = fmaxf(acc[i], 0.0f);
  }
  __syncthreads();
  {
    const int p = tid >> 4, c0 = (tid & 15) * 16;
    float acc[16];
#pragma unroll
    for (int i = 0; i < 16; ++i) acc[i] = b2[c0+i];
    for (int k = 0; k < 128; ++k){
      const float xv = H1[p][k];
#pragma unroll
      for (int i4 = 0; i4 < 4; ++i4){
        const float4 wv = *(const float4*)&w2[k*256 + c0 + 4*i4];
        acc[4*i4+0]=fmaf(xv,wv.x,acc[4*i4+0]);
        acc[4*i4+1]=fmaf(xv,wv.y,acc[4*i4+1]);
        acc[4*i4+2]=fmaf(xv,wv.z,acc[4*i4+2]);
        acc[4*i4+3]=fmaf(xv,wv.w,acc[4*i4+3]);
      }
    }
#pragma unroll
    for (int i = 0; i < 16; ++i) H2[p][c0+i] = fmaxf(acc[i], 0.0f);
  }
  __syncthreads();
  {
    const int pg = tid >> 6, c0 = (tid & 63) * 4;
    float acc[4][4];
#pragma unroll
    for (int p4 = 0; p4 < 4; ++p4)
#pragma unroll
      for (int i = 0; i < 4; ++i) acc[p4][i] = b3[c0+i];
    for (int k = 0; k < 256; ++k){
      const float4 wv = *(const float4*)&w3[k*256 + c0];
#pragma unroll
      for (int p4 = 0; p4 < 4; ++p4){
        const float xv = H2[pg*4+p4][k];
        acc[p4][0]=fmaf(xv,wv.x,acc[p4][0]);
        acc[p4][1]=fmaf(xv,wv.y,acc[p4][1]);
        acc[p4][2]=fmaf(xv,wv.z,acc[p4][2]);
        acc[p4][3]=fmaf(xv,wv.w,acc[p4][3]);
      }
    }
    float4 mx;
    mx.x = fmaxf(fmaxf(fmaxf(acc[0][0],0.f),fmaxf(acc[1][0],0.f)),
                 fmaxf(fmaxf(acc[2][0],0.f),fmaxf(acc[3][0],0.f)));
    mx.y = fmaxf(fmaxf(fmaxf(acc[0][1],0.f),fmaxf(acc[1][1],0.f)),
                 fmaxf(fmaxf(acc[2][1],0.f),fmaxf(acc[3][1],0.f)));
    mx.z = fmaxf(fmaxf(fmaxf(acc[0][2],0.f),fmaxf(acc[1][2],0.f)),
                 fmaxf(fmaxf(acc[2][2],0.f),fmaxf(acc[3][2],0.f)));
    mx.w = fmaxf(fmaxf(fmaxf(acc[0][3],0.f),fmaxf(acc[1][3],0.f)),
                 fmaxf(fmaxf(acc[2][3],0.f),fmaxf(acc[3][3],0.f)));
    *(float4*)&PM[pg][c0] = mx;
  }
  __syncthreads();
  {
    const float m = fmaxf(fmaxf(PM[0][tid], PM[1][tid]),
                          fmaxf(PM[2][tid], PM[3][tid]));
    atomicMax((int*)(out + b*256 + tid), __float_as_int(m));
  }
}

// ---------------------------------------------------------------------------
extern "C" void kernel_launch(void* const* d_in, const int* in_sizes, int n_in,
                              void* d_out, int out_size, void* d_ws, size_t ws_size,
                              hipStream_t stream)
{
  const float* pts  = (const float*)d_in[0];
  // d_in[1] = batch (int64) -- implied by uniform layout, unused
  const float* p1w1 = (const float*)d_in[2];
  const float* p1b1 = (const float*)d_in[3];
  const float* p1w2 = (const float*)d_in[4];
  const float* p1b2 = (const float*)d_in[5];
  const float* p1w3 = (const float*)d_in[6];
  const float* p1b3 = (const float*)d_in[7];
  const float* p2w1 = (const float*)d_in[8];
  const float* p2b1 = (const float*)d_in[9];
  const float* p2w2 = (const float*)d_in[10];
  const float* p2b2 = (const float*)d_in[11];
  const float* p2w3 = (const float*)d_in[12];
  const float* p2b3 = (const float*)d_in[13];
  const float* p3w1 = (const float*)d_in[14];
  const float* p3b1 = (const float*)d_in[15];
  const float* p3w2 = (const float*)d_in[16];
  const float* p3b2 = (const float*)d_in[17];
  const float* p3w3 = (const float*)d_in[18];
  const float* p3b3 = (const float*)d_in[19];

  float* ws = (float*)d_ws;
  size_t o = 0;
  float* npts1 = ws + o; o += (size_t)8*2048*3;
  float* f1    = ws + o; o += (size_t)8*2048*16;
  float* f2    = ws + o; o += (size_t)8*512*64;

  fps_kernel<8192,256,2048><<<8, 256, 0, stream>>>(pts, npts1);
  knn_mlp1_kernel<8192,2048,2048><<<8*32, 256, 0, stream>>>(npts1, pts,
      p1w1, p1b1, p1w2, p1b2, p1w3, p1b3, f1);
  // fps level-2 eliminated: fps(npts1,512) == npts1[:512] (nesting property)
  knn_mlp2_kernel<<<8*8, 256, 0, stream>>>(npts1, npts1, f1,
      p2w1, p2b1, p2w2, p2b2, p2w3, p2b3, f2);
  hipMemsetAsync(d_out, 0, (size_t)out_size * sizeof(float), stream);
  mlp3_kernel<<<8*32, 256, 0, stream>>>(f2,
      p3w1, p3b1, p3w2, p3b2, p3w3, p3b3, (float*)d_out);
}